// Round 9
// baseline (2889.817 us; speedup 1.0000x reference)
//
#include <hip/hip_runtime.h>
#include <hip/hip_bf16.h>
#include <cstdint>
#include <cstddef>

#define NN 30000
#define EE 150000
#define NCH 15000   // nodes per chunk (2 chunks)
#define ECH 80000   // m32 rows budget per chunk (~75000 expected)

using u16 = unsigned short;
using u32 = unsigned int;

__device__ __forceinline__ float bl2f(u16 u) { return __uint_as_float(((u32)u) << 16); }
__device__ __forceinline__ u16 f2bl(float f) {
    u32 x = __float_as_uint(f);
    return (u16)((x + 0x7fffu + ((x >> 16) & 1u)) >> 16);
}
__device__ __forceinline__ u32 pack2(float a, float b) {
    return (u32)f2bl(a) | ((u32)f2bl(b) << 16);
}

// ---------------- CSR build ----------------
__global__ void k_count(const int* __restrict__ dst, int* __restrict__ cnt) {
    int e = blockIdx.x * 256 + threadIdx.x;
    if (e < EE) atomicAdd(&cnt[dst[e]], 1);
}

__global__ void k_scan(const int* __restrict__ cnt, int* __restrict__ offs) {
    __shared__ int ss[1024];
    int t = threadIdx.x;
    int base = t * 30;
    int s = 0;
    for (int i = 0; i < 30; i++) { int idx = base + i; if (idx < NN) s += cnt[idx]; }
    ss[t] = s; __syncthreads();
    for (int off = 1; off < 1024; off <<= 1) {
        int v = (t >= off) ? ss[t - off] : 0;
        __syncthreads();
        ss[t] += v;
        __syncthreads();
    }
    int run = (t == 0) ? 0 : ss[t - 1];
    for (int i = 0; i < 30; i++) {
        int idx = base + i;
        if (idx < NN) { offs[idx] = run; run += cnt[idx]; }
    }
    if (t == 1023) offs[NN] = run;
}

__global__ void k_scatter(const int* __restrict__ src, const int* __restrict__ dst,
                          const int* __restrict__ offs, int* __restrict__ fill,
                          int* __restrict__ csr) {
    int e = blockIdx.x * 256 + threadIdx.x;
    if (e < EE) {
        int d = dst[e];
        int p = offs[d] + atomicAdd(&fill[d], 1);
        csr[p] = src[e];
    }
}

// ---------------- k_wqt: transpose agg-part of W_post into c-major layout --------
__global__ void k_wqt(const float* __restrict__ W_post, float* __restrict__ wqt) {
    int idx = blockIdx.x * 256 + threadIdx.x;
    if (idx >= 270000) return;
    int j = idx % 15;
    int grp = (idx / 15) % 3;
    int s4 = (idx / 45) % 4;
    int c = (idx / 180) % 75;
    int lt = idx / 13500;
    wqt[idx] = W_post[(size_t)lt * 975 * 15 + (size_t)(75 + grp * 300 + s4 * 75 + c) * 15 + j];
}

// ---------------- pre linear: hN[n][80] f32 + hB[n][40] bf16 pairs ----------------
__global__ void k_pre(const float* __restrict__ x, const float* __restrict__ pw,
                      const float* __restrict__ pb, float* __restrict__ hN,
                      u32* __restrict__ hB) {
    int n = blockIdx.x * 256 + threadIdx.x;
    if (n >= NN) return;
    float x0 = x[2 * n], x1 = x[2 * n + 1];
    float buf[80];
#pragma unroll
    for (int c = 0; c < 80; c++)
        buf[c] = (c < 75) ? fmaf(x0, pw[c], fmaf(x1, pw[75 + c], pb[c])) : 0.f;
    float4* dstp = (float4*)(hN + (size_t)n * 80);
#pragma unroll
    for (int w = 0; w < 20; w++)
        dstp[w] = make_float4(buf[4 * w], buf[4 * w + 1], buf[4 * w + 2], buf[4 * w + 3]);
    uint4* bp4 = (uint4*)(hB + (size_t)n * 40);
#pragma unroll
    for (int w = 0; w < 10; w++)
        bp4[w] = make_uint4(pack2(buf[8 * w], buf[8 * w + 1]), pack2(buf[8 * w + 2], buf[8 * w + 3]),
                            pack2(buf[8 * w + 4], buf[8 * w + 5]), pack2(buf[8 * w + 6], buf[8 * w + 7]));
}

// ---- shared inner: 75 outputs (one tower) of bf16 h(75) x Wp row-major ----
__device__ __forceinline__ void gemm75(const uint4* __restrict__ hp4,
                                       const float* __restrict__ wt,
                                       float* acc) {
    for (int fc = 0; fc < 9; fc++) {
        uint4 a = hp4[fc];
        float hf[8];
        hf[0] = __uint_as_float(a.x << 16); hf[1] = __uint_as_float(a.x & 0xffff0000u);
        hf[2] = __uint_as_float(a.y << 16); hf[3] = __uint_as_float(a.y & 0xffff0000u);
        hf[4] = __uint_as_float(a.z << 16); hf[5] = __uint_as_float(a.z & 0xffff0000u);
        hf[6] = __uint_as_float(a.w << 16); hf[7] = __uint_as_float(a.w & 0xffff0000u);
#pragma unroll
        for (int k = 0; k < 8; k++) {
            float in = hf[k];
            const float* wr = wt + (fc * 8 + k) * 75;
#pragma unroll
            for (int j = 0; j < 75; j++) acc[j] = fmaf(in, wr[j], acc[j]);
        }
    }
    // tail feats 72..74
    uint4 a = hp4[9];
    float t0 = __uint_as_float(a.x << 16), t1 = __uint_as_float(a.x & 0xffff0000u);
    float t2 = __uint_as_float(a.y << 16);
#pragma unroll
    for (int j = 0; j < 75; j++) acc[j] = fmaf(t0, wt[72 * 75 + j], acc[j]);
#pragma unroll
    for (int j = 0; j < 75; j++) acc[j] = fmaf(t1, wt[73 * 75 + j], acc[j]);
#pragma unroll
    for (int j = 0; j < 75; j++) acc[j] = fmaf(t2, wt[74 * 75 + j], acc[j]);
}

// ---------------- k_base: thread-per-node x 5 towers -> baseb32[n][190] --------
__global__ __launch_bounds__(256) void k_base(const u32* __restrict__ hB,
                                              const float* __restrict__ Wp,
                                              const float* __restrict__ bp,
                                              u32* __restrict__ baseb32) {
    int n = blockIdx.x * 256 + threadIdx.x;
    int t = blockIdx.y;               // tower 0..4, block-uniform
    if (n >= NN) return;
    const uint4* hp4 = (const uint4*)(hB + (size_t)n * 40);
    const float* wt = Wp + (size_t)t * 150 * 75;      // dst half
    float acc[75];
#pragma unroll
    for (int j = 0; j < 75; j++) acc[j] = bp[t * 75 + j];
    gemm75(hp4, wt, acc);
    u32* row = baseb32 + (size_t)n * 190 + t * 38;
#pragma unroll
    for (int w = 0; w < 37; w++) row[w] = pack2(acc[2 * w], acc[2 * w + 1]);
    row[37] = pack2(acc[74], 0.f);
}

// ---------------- k_msg: thread-per-edge x 5 towers -> m32[row][190] ----------
__global__ __launch_bounds__(256) void k_msg(const u32* __restrict__ hB,
                                             const int* __restrict__ csr,
                                             const float* __restrict__ Wp,
                                             u32* __restrict__ m32,
                                             const int* __restrict__ offs,
                                             int n0, int n1) {
    int e_begin = offs[n0], e_end = offs[n1];
    int e = e_begin + blockIdx.x * 256 + threadIdx.x;
    if (e >= e_end) return;
    int t = blockIdx.y;               // tower 0..4, block-uniform
    int su = csr[e];
    const uint4* hp4 = (const uint4*)(hB + (size_t)su * 40);
    const float* wt = Wp + ((size_t)t * 150 + 75) * 75;   // src half
    float acc[75];
#pragma unroll
    for (int j = 0; j < 75; j++) acc[j] = 0.f;
    gemm75(hp4, wt, acc);
    u32* row = m32 + (size_t)(e - e_begin) * 190 + t * 38;
#pragma unroll
    for (int w = 0; w < 37; w++) row[w] = pack2(acc[2 * w], acc[2 * w + 1]);
    row[37] = pack2(acc[74], 0.f);
}

// ---------------- k_agg: per-node stats over chunk-relative m32 rows ----------------
__global__ __launch_bounds__(192) void k_agg(const u32* __restrict__ m32,
                                             const int* __restrict__ offs,
                                             const u32* __restrict__ baseb32,
                                             u32* __restrict__ agg32,
                                             int n0, int n1) {
    int q = threadIdx.x;
    if (q >= 190) return;
    int e_base = offs[n0];
    int t = q / 38, w = q % 38;
    int c0 = 2 * w, c1 = c0 + 1;
    bool has1 = c1 < 75;
    for (int v = n0 + blockIdx.x; v < n1; v += gridDim.x) {
        int e0 = offs[v], e1 = offs[v + 1];
        float s0 = 0.f, s1 = 0.f, sq0 = 0.f, sq1 = 0.f;
        float mn0 = 3.4e38f, mn1 = 3.4e38f, mx0 = -3.4e38f, mx1 = -3.4e38f;
        for (int e = e0; e < e1; e++) {
            u32 wd = m32[(size_t)(e - e_base) * 190 + q];
            float x0 = bl2f((u16)(wd & 0xffffu)), x1 = bl2f((u16)(wd >> 16));
            s0 += x0; sq0 = fmaf(x0, x0, sq0); mn0 = fminf(mn0, x0); mx0 = fmaxf(mx0, x0);
            s1 += x1; sq1 = fmaf(x1, x1, sq1); mn1 = fminf(mn1, x1); mx1 = fmaxf(mx1, x1);
        }
        int deg = e1 - e0;
        u32 bw = baseb32[(size_t)v * 190 + q];
        float b0 = bl2f((u16)(bw & 0xffffu)), b1 = bl2f((u16)(bw >> 16));
        float mean0, mean1, mnf0, mnf1, mxf0, mxf1, sd0, sd1;
        if (deg > 0) {
            float im = 1.f / (float)deg;
            float mm0 = s0 * im, mm1 = s1 * im;
            float v0 = fmaxf(fmaf(-mm0, mm0, sq0 * im), 0.f);
            float v1 = fmaxf(fmaf(-mm1, mm1, sq1 * im), 0.f);
            sd0 = sqrtf(v0 + 1e-5f); sd1 = sqrtf(v1 + 1e-5f);
            mean0 = b0 + mm0; mean1 = b1 + mm1;
            mnf0 = b0 + mn0;  mnf1 = b1 + mn1;
            mxf0 = b0 + mx0;  mxf1 = b1 + mx1;
        } else {
            float sde = sqrtf(1e-5f);
            mean0 = mean1 = mnf0 = mnf1 = mxf0 = mxf1 = 0.f;
            sd0 = sd1 = sde;
        }
        u32* ap = agg32 + (size_t)(v - n0) * 768;
        ap[t * 152 + c0] = pack2(mean0, mnf0);
        ap[t * 152 + 76 + c0] = pack2(mxf0, sd0);
        if (has1) {
            ap[t * 152 + c1] = pack2(mean1, mnf1);
            ap[t * 152 + 76 + c1] = pack2(mxf1, sd1);
        }
    }
}

// ---------------- k_post: thread-per-node, one tower, c-major transposed weights ----
__global__ __launch_bounds__(256) void k_post(const float* __restrict__ hN,
                                              const int* __restrict__ offs,
                                              const u32* __restrict__ agg32,
                                              const float* __restrict__ Wq,
                                              const float* __restrict__ wqt_l,
                                              const float* __restrict__ bq,
                                              const float* __restrict__ adl_p,
                                              float* __restrict__ tmp,
                                              int n0, int n1) {
    int t = blockIdx.x;
    int n = n0 + blockIdx.y * 256 + threadIdx.x;
    if (n >= n1) return;
    float adl = adl_p[0];
    int deg = offs[n + 1] - offs[n];
    float dc = (float)(deg > 0 ? deg : 1);
    float amp = log1pf(dc) / adl;
    float inv = 1.f / amp;
    const float* wt = Wq + (size_t)t * 975 * 15;       // h-part (rows 0..74, sequential)
    const float* wq = wqt_l + (size_t)t * 13500;       // agg-part, c-major contiguous
    float acc[15];
#pragma unroll
    for (int j = 0; j < 15; j++) acc[j] = bq[t * 15 + j];
    const float4* hp4 = (const float4*)(hN + (size_t)n * 80);
#pragma unroll
    for (int fq = 0; fq < 19; fq++) {
        float4 h4 = hp4[fq];
#pragma unroll
        for (int k2 = 0; k2 < 4; k2++) {
            int kk = fq * 4 + k2;
            if (kk < 75) {
                float in = (k2 == 0) ? h4.x : (k2 == 1) ? h4.y : (k2 == 2) ? h4.z : h4.w;
                const float* wr = wt + kk * 15;
#pragma unroll
                for (int j = 0; j < 15; j++) acc[j] = fmaf(in, wr[j], acc[j]);
            }
        }
    }
    const uint4* apA = (const uint4*)(agg32 + (size_t)(n - n0) * 768 + t * 152);
    const uint4* apB = (const uint4*)(agg32 + (size_t)(n - n0) * 768 + t * 152 + 76);
    for (int cq = 0; cq < 19; cq++) {
        uint4 A = apA[cq];
        uint4 B = apB[cq];
#pragma unroll
        for (int i = 0; i < 4; i++) {
            int c = cq * 4 + i;
            if (c < 75) {
                u32 wA = (i == 0) ? A.x : (i == 1) ? A.y : (i == 2) ? A.z : A.w;
                u32 wB = (i == 0) ? B.x : (i == 1) ? B.y : (i == 2) ? B.z : B.w;
                float vs[4];
                vs[0] = bl2f((u16)(wA & 0xffffu)); vs[1] = bl2f((u16)(wA >> 16));
                vs[2] = bl2f((u16)(wB & 0xffffu)); vs[3] = bl2f((u16)(wB >> 16));
                const float* wc = wq + c * 180;    // 720 B contiguous per c
#pragma unroll
                for (int s4 = 0; s4 < 4; s4++) {
                    float a = vs[s4], aa = a * amp, ai = a * inv;
                    const float* wb = wc + s4 * 45;
#pragma unroll
                    for (int j = 0; j < 15; j++)
                        acc[j] = fmaf(a, wb[j], fmaf(aa, wb[15 + j], fmaf(ai, wb[30 + j], acc[j])));
                }
            }
        }
    }
#pragma unroll
    for (int j = 0; j < 15; j++)
        tmp[(size_t)(t * 15 + j) * NN + n] = acc[j];
}

// ---------------- k_lin2: (nodes x 5 chunks), LDS-staged Wl slice, zF out ----------
__global__ __launch_bounds__(256) void k_lin2(const float* __restrict__ tmp,
                                              const float* __restrict__ Wl,
                                              const float* __restrict__ bl,
                                              float* __restrict__ zF,
                                              float* __restrict__ bsum,
                                              float* __restrict__ bsq) {
    __shared__ __align__(16) float wl[75][16];
    __shared__ float red1[4][15], red2[4][15];
    int p = blockIdx.y;               // output chunk 0..4 (15 channels)
    for (int idx = threadIdx.x; idx < 75 * 15; idx += 256) {
        int k = idx / 15, j = idx % 15;
        wl[k][j] = Wl[k * 75 + p * 15 + j];
    }
    __syncthreads();
    int n = blockIdx.x * 256 + threadIdx.x;
    bool valid = n < NN;
    int nc = valid ? n : NN - 1;
    float acc[15];
#pragma unroll
    for (int j = 0; j < 15; j++) acc[j] = bl[p * 15 + j];
    for (int k = 0; k < 75; k++) {
        float in = tmp[(size_t)k * NN + nc];
        float4 w0 = *(const float4*)&wl[k][0];
        float4 w1 = *(const float4*)&wl[k][4];
        float4 w2 = *(const float4*)&wl[k][8];
        float4 w3 = *(const float4*)&wl[k][12];
        acc[0] = fmaf(in, w0.x, acc[0]);  acc[1] = fmaf(in, w0.y, acc[1]);
        acc[2] = fmaf(in, w0.z, acc[2]);  acc[3] = fmaf(in, w0.w, acc[3]);
        acc[4] = fmaf(in, w1.x, acc[4]);  acc[5] = fmaf(in, w1.y, acc[5]);
        acc[6] = fmaf(in, w1.z, acc[6]);  acc[7] = fmaf(in, w1.w, acc[7]);
        acc[8] = fmaf(in, w2.x, acc[8]);  acc[9] = fmaf(in, w2.y, acc[9]);
        acc[10] = fmaf(in, w2.z, acc[10]); acc[11] = fmaf(in, w2.w, acc[11]);
        acc[12] = fmaf(in, w3.x, acc[12]); acc[13] = fmaf(in, w3.y, acc[13]);
        acc[14] = fmaf(in, w3.z, acc[14]);
    }
    if (valid) {
#pragma unroll
        for (int j = 0; j < 15; j++)
            zF[(size_t)(p * 15 + j) * NN + n] = acc[j];
    }
    float s[15], ss[15];
#pragma unroll
    for (int i = 0; i < 15; i++) {
        float a = valid ? acc[i] : 0.f;
        s[i] = a; ss[i] = a * a;
    }
    for (int d = 32; d > 0; d >>= 1) {
#pragma unroll
        for (int i = 0; i < 15; i++) {
            s[i] += __shfl_down(s[i], d);
            ss[i] += __shfl_down(ss[i], d);
        }
    }
    int wave = threadIdx.x >> 6, lane = threadIdx.x & 63;
    if (lane == 0) {
#pragma unroll
        for (int i = 0; i < 15; i++) { red1[wave][i] = s[i]; red2[wave][i] = ss[i]; }
    }
    __syncthreads();
    if (threadIdx.x < 15) {
        int i = threadIdx.x;
        float a = red1[0][i] + red1[1][i] + red1[2][i] + red1[3][i];
        float b = red2[0][i] + red2[1][i] + red2[2][i] + red2[3][i];
        atomicAdd(&bsum[p * 15 + i], a);
        atomicAdd(&bsq[p * 15 + i], b);
    }
}

// ---------------- k_bn2: BN + ReLU, zF -> hN f32 + hB bf16 ----------
__global__ __launch_bounds__(256) void k_bn2(const float* __restrict__ zF,
                                             const float* __restrict__ bsum,
                                             const float* __restrict__ bsq,
                                             const float* __restrict__ g,
                                             const float* __restrict__ b,
                                             float* __restrict__ hN,
                                             u32* __restrict__ hB) {
    int n = blockIdx.x * 256 + threadIdx.x;
    if (n >= NN) return;
    float buf[80];
    for (int c = 0; c < 75; c++) {
        float mu = bsum[c] * (1.f / NN);
        float var = bsq[c] * (1.f / NN) - mu * mu;
        float sc = g[c] * rsqrtf(var + 1e-5f);
        float v = (zF[(size_t)c * NN + n] - mu) * sc + b[c];
        buf[c] = v > 0.f ? v : 0.f;
    }
#pragma unroll
    for (int c = 75; c < 80; c++) buf[c] = 0.f;
    float4* dstp = (float4*)(hN + (size_t)n * 80);
#pragma unroll
    for (int w = 0; w < 20; w++)
        dstp[w] = make_float4(buf[4 * w], buf[4 * w + 1], buf[4 * w + 2], buf[4 * w + 3]);
    uint4* bp4 = (uint4*)(hB + (size_t)n * 40);
#pragma unroll
    for (int w = 0; w < 10; w++)
        bp4[w] = make_uint4(pack2(buf[8 * w], buf[8 * w + 1]), pack2(buf[8 * w + 2], buf[8 * w + 3]),
                            pack2(buf[8 * w + 4], buf[8 * w + 5]), pack2(buf[8 * w + 6], buf[8 * w + 7]));
}

// ---------------- MLP head ----------------
__global__ __launch_bounds__(256) void k_mlp1(const float* __restrict__ hN,
                                              const float* __restrict__ alpha,
                                              const int* __restrict__ batch,
                                              const float* __restrict__ w1,
                                              const float* __restrict__ b1,
                                              float* __restrict__ t1) {
    int n = blockIdx.x * 256 + threadIdx.x;
    if (n >= NN) return;
    float acc[50];
#pragma unroll
    for (int j = 0; j < 50; j++) acc[j] = b1[j];
    const float4* hp4 = (const float4*)(hN + (size_t)n * 80);
#pragma unroll
    for (int fq = 0; fq < 19; fq++) {
        float4 h4 = hp4[fq];
#pragma unroll
        for (int k2 = 0; k2 < 4; k2++) {
            int kk = fq * 4 + k2;
            if (kk < 75) {
                float in = (k2 == 0) ? h4.x : (k2 == 1) ? h4.y : (k2 == 2) ? h4.z : h4.w;
                const float* wr = w1 + kk * 50;
#pragma unroll
                for (int j = 0; j < 50; j++) acc[j] = fmaf(in, wr[j], acc[j]);
            }
        }
    }
    float a = alpha[batch[n]];
    const float* wr = w1 + 75 * 50;
#pragma unroll
    for (int j = 0; j < 50; j++) {
        float v = fmaf(a, wr[j], acc[j]);
        t1[(size_t)j * NN + n] = v > 0.f ? v : 0.f;
    }
}

__global__ void k_mlp2(const float* __restrict__ t1, const float* __restrict__ w2,
                       const float* __restrict__ b2, const float* __restrict__ w3,
                       const float* __restrict__ b3, const float* __restrict__ noise,
                       const float* __restrict__ x, float* __restrict__ out) {
    int n = blockIdx.x * 256 + threadIdx.x;
    if (n >= NN) return;
    float tr[50];
#pragma unroll
    for (int k = 0; k < 50; k++) tr[k] = t1[(size_t)k * NN + n];
    float y = b3[0];
#pragma unroll
    for (int k2 = 0; k2 < 25; k2++) {
        float acc = b2[k2];
#pragma unroll
        for (int k = 0; k < 50; k++) acc = fmaf(tr[k], w2[k * 25 + k2], acc);
        acc = acc > 0.f ? acc : 0.f;
        y = fmaf(acc, w3[k2], y);
    }
    float z = y + noise[n];
    float s = 1.f / (1.f + expf(-z));
    out[n] = s;
    out[NN + n] = x[2 * n];
}

extern "C" void kernel_launch(void* const* d_in, const int* in_sizes, int n_in,
                              void* d_out, int out_size, void* d_ws, size_t ws_size,
                              hipStream_t stream) {
    const float* x      = (const float*)d_in[0];
    const float* alpha  = (const float*)d_in[1];
    const int*   ei     = (const int*)d_in[2];
    const int*   batch  = (const int*)d_in[3];
    const float* noise  = (const float*)d_in[4];
    const float* adl    = (const float*)d_in[5];
    const float* pre_w  = (const float*)d_in[6];
    const float* pre_b  = (const float*)d_in[7];
    const float* W_pre  = (const float*)d_in[8];
    const float* b_pre  = (const float*)d_in[9];
    const float* W_post = (const float*)d_in[10];
    const float* b_post = (const float*)d_in[11];
    const float* W_lin  = (const float*)d_in[12];
    const float* b_lin  = (const float*)d_in[13];
    const float* bn_g   = (const float*)d_in[14];
    const float* bn_b   = (const float*)d_in[15];
    const float* mw1    = (const float*)d_in[16];
    const float* mb1    = (const float*)d_in[17];
    const float* mw2    = (const float*)d_in[18];
    const float* mb2    = (const float*)d_in[19];
    const float* mw3    = (const float*)d_in[20];
    const float* mb3    = (const float*)d_in[21];
    (void)in_sizes; (void)n_in; (void)out_size; (void)ws_size;

    char* ws = (char*)d_ws;
    size_t off = 0;
    auto alloc = [&](size_t bytes) -> char* {
        char* p = ws + off;
        off += (bytes + 255) & ~((size_t)255);
        return p;
    };
    float* hN     = (float*)alloc((size_t)NN * 80 * 4);        //  9.6 MB
    u32*   hB     = (u32*)alloc((size_t)NN * 40 * 4);          //  4.8 MB bf16 pairs
    float* zF     = (float*)alloc((size_t)75 * NN * 4);        //  9.0 MB
    float* tmp    = (float*)alloc((size_t)75 * NN * 4);        //  9.0 MB
    u32*   agg32  = (u32*)alloc((size_t)NCH * 768 * 4);        // 46.1 MB
    u32*   baseb32= (u32*)alloc((size_t)NN * 190 * 4);         // 22.8 MB
    u32*   m32    = (u32*)alloc((size_t)ECH * 190 * 4);        // 60.8 MB
    float* wqt    = (float*)alloc((size_t)270000 * 4);         //  1.1 MB
    int*   cnt    = (int*)alloc((size_t)NN * 4);
    int*   offs   = (int*)alloc((size_t)(NN + 1) * 4);
    int*   fill   = (int*)alloc((size_t)NN * 4);
    int*   csr    = (int*)alloc((size_t)EE * 4);
    float* bnsum  = (float*)alloc(4 * 75 * 4);
    float* bnsq   = (float*)alloc(4 * 75 * 4);

    hipMemsetAsync(cnt, 0, (size_t)NN * 4, stream);
    hipMemsetAsync(fill, 0, (size_t)NN * 4, stream);
    hipMemsetAsync(bnsum, 0, 4 * 75 * 4, stream);
    hipMemsetAsync(bnsq, 0, 4 * 75 * 4, stream);

    const int* src = ei;
    const int* dst = ei + EE;
    int eb = (EE + 255) / 256;
    int nb = (NN + 255) / 256;
    int cb = (NCH + 255) / 256;
    int mb = (ECH + 255) / 256;

    k_count<<<eb, 256, 0, stream>>>(dst, cnt);
    k_scan<<<1, 1024, 0, stream>>>(cnt, offs);
    k_scatter<<<eb, 256, 0, stream>>>(src, dst, offs, fill, csr);
    k_pre<<<nb, 256, 0, stream>>>(x, pre_w, pre_b, hN, hB);
    k_wqt<<<(270000 + 255) / 256, 256, 0, stream>>>(W_post, wqt);

    for (int l = 0; l < 4; l++) {
        const float* Wp  = W_pre + (size_t)l * 5 * 150 * 75;
        const float* bp  = b_pre + l * 375;
        const float* Wq  = W_post + (size_t)l * 5 * 975 * 15;
        const float* wqtl= wqt + (size_t)l * 67500;
        const float* bq  = b_post + l * 75;
        const float* Wl  = W_lin + l * 75 * 75;
        const float* blp = b_lin + l * 75;
        k_base<<<dim3(nb, 5), 256, 0, stream>>>(hB, Wp, bp, baseb32);
        for (int ch = 0; ch < 2; ch++) {
            int n0 = ch * NCH, n1 = n0 + NCH;
            k_msg<<<dim3(mb, 5), 256, 0, stream>>>(hB, csr, Wp, m32, offs, n0, n1);
            k_agg<<<2048, 192, 0, stream>>>(m32, offs, baseb32, agg32, n0, n1);
            k_post<<<dim3(5, cb), 256, 0, stream>>>(hN, offs, agg32, Wq, wqtl, bq, adl, tmp, n0, n1);
        }
        k_lin2<<<dim3(nb, 5), 256, 0, stream>>>(tmp, Wl, blp, zF, bnsum + l * 75, bnsq + l * 75);
        k_bn2<<<nb, 256, 0, stream>>>(zF, bnsum + l * 75, bnsq + l * 75,
                                      bn_g + l * 75, bn_b + l * 75, hN, hB);
    }

    float* t1 = tmp;
    k_mlp1<<<nb, 256, 0, stream>>>(hN, alpha, batch, mw1, mb1, t1);
    k_mlp2<<<nb, 256, 0, stream>>>(t1, mw2, mb2, mw3, mb3, noise, x, (float*)d_out);
}

// Round 10
// 2514.032 us; speedup vs baseline: 1.1495x; 1.1495x over previous
//
#include <hip/hip_runtime.h>
#include <hip/hip_bf16.h>
#include <cstdint>
#include <cstddef>

#define NN 30000
#define EE 150000
#define NCH 15000   // nodes per chunk (2 chunks)
#define ECH 80000   // m32 rows budget per chunk (~75000 expected)

using u16 = unsigned short;
using u32 = unsigned int;

__device__ __forceinline__ float bl2f(u16 u) { return __uint_as_float(((u32)u) << 16); }
__device__ __forceinline__ u16 f2bl(float f) {
    u32 x = __float_as_uint(f);
    return (u16)((x + 0x7fffu + ((x >> 16) & 1u)) >> 16);
}
__device__ __forceinline__ u32 pack2(float a, float b) {
    return (u32)f2bl(a) | ((u32)f2bl(b) << 16);
}

// ---------------- CSR build ----------------
__global__ void k_count(const int* __restrict__ dst, int* __restrict__ cnt) {
    int e = blockIdx.x * 256 + threadIdx.x;
    if (e < EE) atomicAdd(&cnt[dst[e]], 1);
}

__global__ void k_scan(const int* __restrict__ cnt, int* __restrict__ offs) {
    __shared__ int ss[1024];
    int t = threadIdx.x;
    int base = t * 30;
    int s = 0;
    for (int i = 0; i < 30; i++) { int idx = base + i; if (idx < NN) s += cnt[idx]; }
    ss[t] = s; __syncthreads();
    for (int off = 1; off < 1024; off <<= 1) {
        int v = (t >= off) ? ss[t - off] : 0;
        __syncthreads();
        ss[t] += v;
        __syncthreads();
    }
    int run = (t == 0) ? 0 : ss[t - 1];
    for (int i = 0; i < 30; i++) {
        int idx = base + i;
        if (idx < NN) { offs[idx] = run; run += cnt[idx]; }
    }
    if (t == 1023) offs[NN] = run;
}

__global__ void k_scatter(const int* __restrict__ src, const int* __restrict__ dst,
                          const int* __restrict__ offs, int* __restrict__ fill,
                          int* __restrict__ csr) {
    int e = blockIdx.x * 256 + threadIdx.x;
    if (e < EE) {
        int d = dst[e];
        int p = offs[d] + atomicAdd(&fill[d], 1);
        csr[p] = src[e];
    }
}

// ---------------- k_wqt: transpose agg-part of W_post into c-major layout --------
__global__ void k_wqt(const float* __restrict__ W_post, float* __restrict__ wqt) {
    int idx = blockIdx.x * 256 + threadIdx.x;
    if (idx >= 270000) return;
    int j = idx % 15;
    int grp = (idx / 15) % 3;
    int s4 = (idx / 45) % 4;
    int c = (idx / 180) % 75;
    int lt = idx / 13500;
    wqt[idx] = W_post[(size_t)lt * 975 * 15 + (size_t)(75 + grp * 300 + s4 * 75 + c) * 15 + j];
}

// ---------------- pre linear: hN[n][80] f32 + hB[n][40] bf16 pairs ----------------
__global__ void k_pre(const float* __restrict__ x, const float* __restrict__ pw,
                      const float* __restrict__ pb, float* __restrict__ hN,
                      u32* __restrict__ hB) {
    int n = blockIdx.x * 256 + threadIdx.x;
    if (n >= NN) return;
    float x0 = x[2 * n], x1 = x[2 * n + 1];
    float buf[80];
#pragma unroll
    for (int c = 0; c < 80; c++)
        buf[c] = (c < 75) ? fmaf(x0, pw[c], fmaf(x1, pw[75 + c], pb[c])) : 0.f;
    float4* dstp = (float4*)(hN + (size_t)n * 80);
#pragma unroll
    for (int w = 0; w < 20; w++)
        dstp[w] = make_float4(buf[4 * w], buf[4 * w + 1], buf[4 * w + 2], buf[4 * w + 3]);
    uint4* bp4 = (uint4*)(hB + (size_t)n * 40);
#pragma unroll
    for (int w = 0; w < 10; w++)
        bp4[w] = make_uint4(pack2(buf[8 * w], buf[8 * w + 1]), pack2(buf[8 * w + 2], buf[8 * w + 3]),
                            pack2(buf[8 * w + 4], buf[8 * w + 5]), pack2(buf[8 * w + 6], buf[8 * w + 7]));
}

// ---- unpack helper: float k (0..7) from uint4 of bf16 pairs ----
__device__ __forceinline__ float upk(const uint4& a, int k) {
    u32 u = (k < 2) ? a.x : (k < 4) ? a.y : (k < 6) ? a.z : a.w;
    return __uint_as_float((k & 1) ? (u & 0xffff0000u) : (u << 16));
}

// ---- shared inner: 4 rows x 30 outputs, uniform weights (wA,wB 15-col slices) ----
__device__ __forceinline__ void gemm30q(const uint4* __restrict__ h0,
                                        const uint4* __restrict__ h1,
                                        const uint4* __restrict__ h2,
                                        const uint4* __restrict__ h3,
                                        const float* __restrict__ wA,
                                        const float* __restrict__ wB,
                                        float acc[4][30]) {
    for (int fq = 0; fq < 9; fq++) {
        uint4 a0 = h0[fq], a1 = h1[fq], a2 = h2[fq], a3 = h3[fq];
#pragma unroll
        for (int k = 0; k < 8; k++) {
            float i0 = upk(a0, k), i1 = upk(a1, k), i2 = upk(a2, k), i3 = upk(a3, k);
            const float* ra = wA + (fq * 8 + k) * 75;
            const float* rb = wB + (fq * 8 + k) * 75;
#pragma unroll
            for (int j = 0; j < 15; j++) {
                float w = ra[j];
                acc[0][j] = fmaf(i0, w, acc[0][j]); acc[1][j] = fmaf(i1, w, acc[1][j]);
                acc[2][j] = fmaf(i2, w, acc[2][j]); acc[3][j] = fmaf(i3, w, acc[3][j]);
            }
#pragma unroll
            for (int j = 0; j < 15; j++) {
                float w = rb[j];
                acc[0][15 + j] = fmaf(i0, w, acc[0][15 + j]); acc[1][15 + j] = fmaf(i1, w, acc[1][15 + j]);
                acc[2][15 + j] = fmaf(i2, w, acc[2][15 + j]); acc[3][15 + j] = fmaf(i3, w, acc[3][15 + j]);
            }
        }
    }
    uint4 a0 = h0[9], a1 = h1[9], a2 = h2[9], a3 = h3[9];
#pragma unroll
    for (int k = 0; k < 3; k++) {
        float i0 = upk(a0, k), i1 = upk(a1, k), i2 = upk(a2, k), i3 = upk(a3, k);
        const float* ra = wA + (72 + k) * 75;
        const float* rb = wB + (72 + k) * 75;
#pragma unroll
        for (int j = 0; j < 15; j++) {
            float w = ra[j];
            acc[0][j] = fmaf(i0, w, acc[0][j]); acc[1][j] = fmaf(i1, w, acc[1][j]);
            acc[2][j] = fmaf(i2, w, acc[2][j]); acc[3][j] = fmaf(i3, w, acc[3][j]);
        }
#pragma unroll
        for (int j = 0; j < 15; j++) {
            float w = rb[j];
            acc[0][15 + j] = fmaf(i0, w, acc[0][15 + j]); acc[1][15 + j] = fmaf(i1, w, acc[1][15 + j]);
            acc[2][15 + j] = fmaf(i2, w, acc[2][15 + j]); acc[3][15 + j] = fmaf(i3, w, acc[3][15 + j]);
        }
    }
}

// chunk p (0..12) -> weight slice pointers (15-col groups A and B)
__device__ __forceinline__ void chunk_w(int p, const float* Wp, int half_off,
                                        const float** wA, const float** wB, bool* full) {
    int cg = p * 2;
    int tA = cg / 5, cA = (cg % 5) * 15;
    *full = p < 12;
    int cg1 = *full ? cg + 1 : cg;
    int tB = cg1 / 5, cB = (cg1 % 5) * 15;
    *wA = Wp + ((size_t)tA * 150 + half_off) * 75 + cA;
    *wB = Wp + ((size_t)tB * 150 + half_off) * 75 + cB;
}

// ---------------- k_base: 4 nodes/thread x 13 chunks -> baseb32[n][188] --------
__global__ __launch_bounds__(256) void k_base(const u32* __restrict__ hB,
                                              const float* __restrict__ Wp,
                                              const float* __restrict__ bp,
                                              u32* __restrict__ baseb32) {
    int nq = blockIdx.x * 256 + threadIdx.x;
    if (nq >= 7500) return;
    int n = nq * 4;
    int p = blockIdx.y;
    const float *wA, *wB; bool full;
    chunk_w(p, Wp, 0, &wA, &wB, &full);
    int o0 = p * 30;
    float acc[4][30];
#pragma unroll
    for (int j = 0; j < 15; j++) {
        float b = bp[o0 + j];
        acc[0][j] = b; acc[1][j] = b; acc[2][j] = b; acc[3][j] = b;
    }
#pragma unroll
    for (int j = 0; j < 15; j++) {
        float b = full ? bp[o0 + 15 + j] : 0.f;
        acc[0][15 + j] = b; acc[1][15 + j] = b; acc[2][15 + j] = b; acc[3][15 + j] = b;
    }
    const uint4* h0 = (const uint4*)(hB + (size_t)(n + 0) * 40);
    const uint4* h1 = (const uint4*)(hB + (size_t)(n + 1) * 40);
    const uint4* h2 = (const uint4*)(hB + (size_t)(n + 2) * 40);
    const uint4* h3 = (const uint4*)(hB + (size_t)(n + 3) * 40);
    gemm30q(h0, h1, h2, h3, wA, wB, acc);
#pragma unroll
    for (int e = 0; e < 4; e++) {
        u32* row = baseb32 + (size_t)(n + e) * 188 + p * 15;
        if (full) {
#pragma unroll
            for (int w = 0; w < 15; w++) row[w] = pack2(acc[e][2 * w], acc[e][2 * w + 1]);
        } else {
#pragma unroll
            for (int w = 0; w < 7; w++) row[w] = pack2(acc[e][2 * w], acc[e][2 * w + 1]);
            row[7] = pack2(acc[e][14], 0.f);
        }
    }
}

// ---------------- k_msg: 4 edges/thread x 13 chunks -> m32[row][188] ----------
__global__ __launch_bounds__(256) void k_msg(const u32* __restrict__ hB,
                                             const int* __restrict__ csr,
                                             const float* __restrict__ Wp,
                                             u32* __restrict__ m32,
                                             const int* __restrict__ offs,
                                             int n0, int n1) {
    int e_begin = offs[n0], e_end = offs[n1];
    int e = e_begin + (blockIdx.x * 256 + threadIdx.x) * 4;
    if (e >= e_end) return;
    int p = blockIdx.y;
    const float *wA, *wB; bool full;
    chunk_w(p, Wp, 75, &wA, &wB, &full);
    int e1c = e + 1 < e_end ? e + 1 : e_end - 1;
    int e2c = e + 2 < e_end ? e + 2 : e_end - 1;
    int e3c = e + 3 < e_end ? e + 3 : e_end - 1;
    int s0 = csr[e], s1 = csr[e1c], s2 = csr[e2c], s3 = csr[e3c];
    float acc[4][30];
#pragma unroll
    for (int e4 = 0; e4 < 4; e4++)
#pragma unroll
        for (int j = 0; j < 30; j++) acc[e4][j] = 0.f;
    const uint4* h0 = (const uint4*)(hB + (size_t)s0 * 40);
    const uint4* h1 = (const uint4*)(hB + (size_t)s1 * 40);
    const uint4* h2 = (const uint4*)(hB + (size_t)s2 * 40);
    const uint4* h3 = (const uint4*)(hB + (size_t)s3 * 40);
    gemm30q(h0, h1, h2, h3, wA, wB, acc);
#pragma unroll
    for (int e4 = 0; e4 < 4; e4++) {
        if (e + e4 >= e_end) break;
        u32* row = m32 + (size_t)(e + e4 - e_begin) * 188 + p * 15;
        if (full) {
#pragma unroll
            for (int w = 0; w < 15; w++) row[w] = pack2(acc[e4][2 * w], acc[e4][2 * w + 1]);
        } else {
#pragma unroll
            for (int w = 0; w < 7; w++) row[w] = pack2(acc[e4][2 * w], acc[e4][2 * w + 1]);
            row[7] = pack2(acc[e4][14], 0.f);
        }
    }
}

// ---------------- k_agg: per-node stats over chunk-relative m32 rows (188 layout) ----
__global__ __launch_bounds__(192) void k_agg(const u32* __restrict__ m32,
                                             const int* __restrict__ offs,
                                             const u32* __restrict__ baseb32,
                                             u32* __restrict__ agg32,
                                             int n0, int n1) {
    int q = threadIdx.x;
    if (q >= 188) return;
    int e_base = offs[n0];
    int o0 = 2 * q, o1 = 2 * q + 1;
    bool has1 = o1 < 375;
    int t0 = o0 / 75, c0 = o0 % 75;
    int t1 = has1 ? (o1 / 75) : 0, c1 = has1 ? (o1 % 75) : 0;
    for (int v = n0 + blockIdx.x; v < n1; v += gridDim.x) {
        int e0 = offs[v], e1 = offs[v + 1];
        float s0 = 0.f, s1 = 0.f, sq0 = 0.f, sq1 = 0.f;
        float mn0 = 3.4e38f, mn1 = 3.4e38f, mx0 = -3.4e38f, mx1 = -3.4e38f;
        for (int e = e0; e < e1; e++) {
            u32 w = m32[(size_t)(e - e_base) * 188 + q];
            float x0 = bl2f((u16)(w & 0xffffu)), x1 = bl2f((u16)(w >> 16));
            s0 += x0; sq0 = fmaf(x0, x0, sq0); mn0 = fminf(mn0, x0); mx0 = fmaxf(mx0, x0);
            s1 += x1; sq1 = fmaf(x1, x1, sq1); mn1 = fminf(mn1, x1); mx1 = fmaxf(mx1, x1);
        }
        int deg = e1 - e0;
        u32 bw = baseb32[(size_t)v * 188 + q];
        float b0 = bl2f((u16)(bw & 0xffffu)), b1 = bl2f((u16)(bw >> 16));
        float mean0, mean1, mnf0, mnf1, mxf0, mxf1, sd0, sd1;
        if (deg > 0) {
            float im = 1.f / (float)deg;
            float mm0 = s0 * im, mm1 = s1 * im;
            float v0 = fmaxf(fmaf(-mm0, mm0, sq0 * im), 0.f);
            float v1 = fmaxf(fmaf(-mm1, mm1, sq1 * im), 0.f);
            sd0 = sqrtf(v0 + 1e-5f); sd1 = sqrtf(v1 + 1e-5f);
            mean0 = b0 + mm0; mean1 = b1 + mm1;
            mnf0 = b0 + mn0;  mnf1 = b1 + mn1;
            mxf0 = b0 + mx0;  mxf1 = b1 + mx1;
        } else {
            float sde = sqrtf(1e-5f);
            mean0 = mean1 = mnf0 = mnf1 = mxf0 = mxf1 = 0.f;
            sd0 = sd1 = sde;
        }
        u32* ap = agg32 + (size_t)(v - n0) * 768;
        ap[t0 * 152 + c0] = pack2(mean0, mnf0);
        ap[t0 * 152 + 76 + c0] = pack2(mxf0, sd0);
        if (has1) {
            ap[t1 * 152 + c1] = pack2(mean1, mnf1);
            ap[t1 * 152 + 76 + c1] = pack2(mxf1, sd1);
        }
    }
}

// ---------------- k_post: thread-per-node, one tower, c-major transposed weights ----
__global__ __launch_bounds__(256) void k_post(const float* __restrict__ hN,
                                              const int* __restrict__ offs,
                                              const u32* __restrict__ agg32,
                                              const float* __restrict__ Wq,
                                              const float* __restrict__ wqt_l,
                                              const float* __restrict__ bq,
                                              const float* __restrict__ adl_p,
                                              float* __restrict__ tmp,
                                              int n0, int n1) {
    int t = blockIdx.x;
    int n = n0 + blockIdx.y * 256 + threadIdx.x;
    if (n >= n1) return;
    float adl = adl_p[0];
    int deg = offs[n + 1] - offs[n];
    float dc = (float)(deg > 0 ? deg : 1);
    float amp = log1pf(dc) / adl;
    float inv = 1.f / amp;
    const float* wt = Wq + (size_t)t * 975 * 15;
    const float* wq = wqt_l + (size_t)t * 13500;
    float acc[15];
#pragma unroll
    for (int j = 0; j < 15; j++) acc[j] = bq[t * 15 + j];
    const float4* hp4 = (const float4*)(hN + (size_t)n * 80);
#pragma unroll
    for (int fq = 0; fq < 19; fq++) {
        float4 h4 = hp4[fq];
#pragma unroll
        for (int k2 = 0; k2 < 4; k2++) {
            int kk = fq * 4 + k2;
            if (kk < 75) {
                float in = (k2 == 0) ? h4.x : (k2 == 1) ? h4.y : (k2 == 2) ? h4.z : h4.w;
                const float* wr = wt + kk * 15;
#pragma unroll
                for (int j = 0; j < 15; j++) acc[j] = fmaf(in, wr[j], acc[j]);
            }
        }
    }
    const uint4* apA = (const uint4*)(agg32 + (size_t)(n - n0) * 768 + t * 152);
    const uint4* apB = (const uint4*)(agg32 + (size_t)(n - n0) * 768 + t * 152 + 76);
    for (int cq = 0; cq < 19; cq++) {
        uint4 A = apA[cq];
        uint4 B = apB[cq];
#pragma unroll
        for (int i = 0; i < 4; i++) {
            int c = cq * 4 + i;
            if (c < 75) {
                u32 wA = (i == 0) ? A.x : (i == 1) ? A.y : (i == 2) ? A.z : A.w;
                u32 wB = (i == 0) ? B.x : (i == 1) ? B.y : (i == 2) ? B.z : B.w;
                float vs[4];
                vs[0] = bl2f((u16)(wA & 0xffffu)); vs[1] = bl2f((u16)(wA >> 16));
                vs[2] = bl2f((u16)(wB & 0xffffu)); vs[3] = bl2f((u16)(wB >> 16));
                const float* wc = wq + c * 180;
#pragma unroll
                for (int s4 = 0; s4 < 4; s4++) {
                    float a = vs[s4], aa = a * amp, ai = a * inv;
                    const float* wb = wc + s4 * 45;
#pragma unroll
                    for (int j = 0; j < 15; j++)
                        acc[j] = fmaf(a, wb[j], fmaf(aa, wb[15 + j], fmaf(ai, wb[30 + j], acc[j])));
                }
            }
        }
    }
#pragma unroll
    for (int j = 0; j < 15; j++)
        tmp[(size_t)(t * 15 + j) * NN + n] = acc[j];
}

// ---------------- k_lin2: (nodes x 5 chunks), LDS-staged Wl slice, zF out ----------
__global__ __launch_bounds__(256) void k_lin2(const float* __restrict__ tmp,
                                              const float* __restrict__ Wl,
                                              const float* __restrict__ bl,
                                              float* __restrict__ zF,
                                              float* __restrict__ bsum,
                                              float* __restrict__ bsq) {
    __shared__ __align__(16) float wl[75][16];
    __shared__ float red1[4][15], red2[4][15];
    int p = blockIdx.y;
    for (int idx = threadIdx.x; idx < 75 * 15; idx += 256) {
        int k = idx / 15, j = idx % 15;
        wl[k][j] = Wl[k * 75 + p * 15 + j];
    }
    __syncthreads();
    int n = blockIdx.x * 256 + threadIdx.x;
    bool valid = n < NN;
    int nc = valid ? n : NN - 1;
    float acc[15];
#pragma unroll
    for (int j = 0; j < 15; j++) acc[j] = bl[p * 15 + j];
    for (int k = 0; k < 75; k++) {
        float in = tmp[(size_t)k * NN + nc];
        float4 w0 = *(const float4*)&wl[k][0];
        float4 w1 = *(const float4*)&wl[k][4];
        float4 w2 = *(const float4*)&wl[k][8];
        float4 w3 = *(const float4*)&wl[k][12];
        acc[0] = fmaf(in, w0.x, acc[0]);  acc[1] = fmaf(in, w0.y, acc[1]);
        acc[2] = fmaf(in, w0.z, acc[2]);  acc[3] = fmaf(in, w0.w, acc[3]);
        acc[4] = fmaf(in, w1.x, acc[4]);  acc[5] = fmaf(in, w1.y, acc[5]);
        acc[6] = fmaf(in, w1.z, acc[6]);  acc[7] = fmaf(in, w1.w, acc[7]);
        acc[8] = fmaf(in, w2.x, acc[8]);  acc[9] = fmaf(in, w2.y, acc[9]);
        acc[10] = fmaf(in, w2.z, acc[10]); acc[11] = fmaf(in, w2.w, acc[11]);
        acc[12] = fmaf(in, w3.x, acc[12]); acc[13] = fmaf(in, w3.y, acc[13]);
        acc[14] = fmaf(in, w3.z, acc[14]);
    }
    if (valid) {
#pragma unroll
        for (int j = 0; j < 15; j++)
            zF[(size_t)(p * 15 + j) * NN + n] = acc[j];
    }
    float s[15], ss[15];
#pragma unroll
    for (int i = 0; i < 15; i++) {
        float a = valid ? acc[i] : 0.f;
        s[i] = a; ss[i] = a * a;
    }
    for (int d = 32; d > 0; d >>= 1) {
#pragma unroll
        for (int i = 0; i < 15; i++) {
            s[i] += __shfl_down(s[i], d);
            ss[i] += __shfl_down(ss[i], d);
        }
    }
    int wave = threadIdx.x >> 6, lane = threadIdx.x & 63;
    if (lane == 0) {
#pragma unroll
        for (int i = 0; i < 15; i++) { red1[wave][i] = s[i]; red2[wave][i] = ss[i]; }
    }
    __syncthreads();
    if (threadIdx.x < 15) {
        int i = threadIdx.x;
        float a = red1[0][i] + red1[1][i] + red1[2][i] + red1[3][i];
        float b = red2[0][i] + red2[1][i] + red2[2][i] + red2[3][i];
        atomicAdd(&bsum[p * 15 + i], a);
        atomicAdd(&bsq[p * 15 + i], b);
    }
}

// ---------------- k_bn2: BN + ReLU, zF -> hN f32 + hB bf16 ----------
__global__ __launch_bounds__(256) void k_bn2(const float* __restrict__ zF,
                                             const float* __restrict__ bsum,
                                             const float* __restrict__ bsq,
                                             const float* __restrict__ g,
                                             const float* __restrict__ b,
                                             float* __restrict__ hN,
                                             u32* __restrict__ hB) {
    int n = blockIdx.x * 256 + threadIdx.x;
    if (n >= NN) return;
    float buf[80];
    for (int c = 0; c < 75; c++) {
        float mu = bsum[c] * (1.f / NN);
        float var = bsq[c] * (1.f / NN) - mu * mu;
        float sc = g[c] * rsqrtf(var + 1e-5f);
        float v = (zF[(size_t)c * NN + n] - mu) * sc + b[c];
        buf[c] = v > 0.f ? v : 0.f;
    }
#pragma unroll
    for (int c = 75; c < 80; c++) buf[c] = 0.f;
    float4* dstp = (float4*)(hN + (size_t)n * 80);
#pragma unroll
    for (int w = 0; w < 20; w++)
        dstp[w] = make_float4(buf[4 * w], buf[4 * w + 1], buf[4 * w + 2], buf[4 * w + 3]);
    uint4* bp4 = (uint4*)(hB + (size_t)n * 40);
#pragma unroll
    for (int w = 0; w < 10; w++)
        bp4[w] = make_uint4(pack2(buf[8 * w], buf[8 * w + 1]), pack2(buf[8 * w + 2], buf[8 * w + 3]),
                            pack2(buf[8 * w + 4], buf[8 * w + 5]), pack2(buf[8 * w + 6], buf[8 * w + 7]));
}

// ---------------- MLP head ----------------
__global__ __launch_bounds__(256) void k_mlp1(const float* __restrict__ hN,
                                              const float* __restrict__ alpha,
                                              const int* __restrict__ batch,
                                              const float* __restrict__ w1,
                                              const float* __restrict__ b1,
                                              float* __restrict__ t1) {
    int n = blockIdx.x * 256 + threadIdx.x;
    if (n >= NN) return;
    float acc[50];
#pragma unroll
    for (int j = 0; j < 50; j++) acc[j] = b1[j];
    const float4* hp4 = (const float4*)(hN + (size_t)n * 80);
#pragma unroll
    for (int fq = 0; fq < 19; fq++) {
        float4 h4 = hp4[fq];
#pragma unroll
        for (int k2 = 0; k2 < 4; k2++) {
            int kk = fq * 4 + k2;
            if (kk < 75) {
                float in = (k2 == 0) ? h4.x : (k2 == 1) ? h4.y : (k2 == 2) ? h4.z : h4.w;
                const float* wr = w1 + kk * 50;
#pragma unroll
                for (int j = 0; j < 50; j++) acc[j] = fmaf(in, wr[j], acc[j]);
            }
        }
    }
    float a = alpha[batch[n]];
    const float* wr = w1 + 75 * 50;
#pragma unroll
    for (int j = 0; j < 50; j++) {
        float v = fmaf(a, wr[j], acc[j]);
        t1[(size_t)j * NN + n] = v > 0.f ? v : 0.f;
    }
}

__global__ void k_mlp2(const float* __restrict__ t1, const float* __restrict__ w2,
                       const float* __restrict__ b2, const float* __restrict__ w3,
                       const float* __restrict__ b3, const float* __restrict__ noise,
                       const float* __restrict__ x, float* __restrict__ out) {
    int n = blockIdx.x * 256 + threadIdx.x;
    if (n >= NN) return;
    float tr[50];
#pragma unroll
    for (int k = 0; k < 50; k++) tr[k] = t1[(size_t)k * NN + n];
    float y = b3[0];
#pragma unroll
    for (int k2 = 0; k2 < 25; k2++) {
        float acc = b2[k2];
#pragma unroll
        for (int k = 0; k < 50; k++) acc = fmaf(tr[k], w2[k * 25 + k2], acc);
        acc = acc > 0.f ? acc : 0.f;
        y = fmaf(acc, w3[k2], y);
    }
    float z = y + noise[n];
    float s = 1.f / (1.f + expf(-z));
    out[n] = s;
    out[NN + n] = x[2 * n];
}

extern "C" void kernel_launch(void* const* d_in, const int* in_sizes, int n_in,
                              void* d_out, int out_size, void* d_ws, size_t ws_size,
                              hipStream_t stream) {
    const float* x      = (const float*)d_in[0];
    const float* alpha  = (const float*)d_in[1];
    const int*   ei     = (const int*)d_in[2];
    const int*   batch  = (const int*)d_in[3];
    const float* noise  = (const float*)d_in[4];
    const float* adl    = (const float*)d_in[5];
    const float* pre_w  = (const float*)d_in[6];
    const float* pre_b  = (const float*)d_in[7];
    const float* W_pre  = (const float*)d_in[8];
    const float* b_pre  = (const float*)d_in[9];
    const float* W_post = (const float*)d_in[10];
    const float* b_post = (const float*)d_in[11];
    const float* W_lin  = (const float*)d_in[12];
    const float* b_lin  = (const float*)d_in[13];
    const float* bn_g   = (const float*)d_in[14];
    const float* bn_b   = (const float*)d_in[15];
    const float* mw1    = (const float*)d_in[16];
    const float* mb1    = (const float*)d_in[17];
    const float* mw2    = (const float*)d_in[18];
    const float* mb2    = (const float*)d_in[19];
    const float* mw3    = (const float*)d_in[20];
    const float* mb3    = (const float*)d_in[21];
    (void)in_sizes; (void)n_in; (void)out_size; (void)ws_size;

    char* ws = (char*)d_ws;
    size_t off = 0;
    auto alloc = [&](size_t bytes) -> char* {
        char* p = ws + off;
        off += (bytes + 255) & ~((size_t)255);
        return p;
    };
    float* hN     = (float*)alloc((size_t)NN * 80 * 4);        //  9.6 MB
    u32*   hB     = (u32*)alloc((size_t)NN * 40 * 4);          //  4.8 MB
    float* zF     = (float*)alloc((size_t)75 * NN * 4);        //  9.0 MB
    float* tmp    = (float*)alloc((size_t)75 * NN * 4);        //  9.0 MB
    u32*   agg32  = (u32*)alloc((size_t)NCH * 768 * 4);        // 46.1 MB
    u32*   baseb32= (u32*)alloc((size_t)NN * 188 * 4);         // 22.6 MB
    u32*   m32    = (u32*)alloc((size_t)ECH * 188 * 4);        // 60.2 MB
    float* wqt    = (float*)alloc((size_t)270000 * 4);         //  1.1 MB
    int*   cnt    = (int*)alloc((size_t)NN * 4);
    int*   offs   = (int*)alloc((size_t)(NN + 1) * 4);
    int*   fill   = (int*)alloc((size_t)NN * 4);
    int*   csr    = (int*)alloc((size_t)EE * 4);
    float* bnsum  = (float*)alloc(4 * 75 * 4);
    float* bnsq   = (float*)alloc(4 * 75 * 4);

    hipMemsetAsync(cnt, 0, (size_t)NN * 4, stream);
    hipMemsetAsync(fill, 0, (size_t)NN * 4, stream);
    hipMemsetAsync(bnsum, 0, 4 * 75 * 4, stream);
    hipMemsetAsync(bnsq, 0, 4 * 75 * 4, stream);

    const int* src = ei;
    const int* dst = ei + EE;
    int eb = (EE + 255) / 256;
    int nb = (NN + 255) / 256;
    int cb = (NCH + 255) / 256;
    int nq = (7500 + 255) / 256;             // node quads
    int mq = (ECH / 4 + 255) / 256;          // edge quads (worst case)

    k_count<<<eb, 256, 0, stream>>>(dst, cnt);
    k_scan<<<1, 1024, 0, stream>>>(cnt, offs);
    k_scatter<<<eb, 256, 0, stream>>>(src, dst, offs, fill, csr);
    k_pre<<<nb, 256, 0, stream>>>(x, pre_w, pre_b, hN, hB);
    k_wqt<<<(270000 + 255) / 256, 256, 0, stream>>>(W_post, wqt);

    for (int l = 0; l < 4; l++) {
        const float* Wp  = W_pre + (size_t)l * 5 * 150 * 75;
        const float* bp  = b_pre + l * 375;
        const float* Wq  = W_post + (size_t)l * 5 * 975 * 15;
        const float* wqtl= wqt + (size_t)l * 67500;
        const float* bq  = b_post + l * 75;
        const float* Wl  = W_lin + l * 75 * 75;
        const float* blp = b_lin + l * 75;
        k_base<<<dim3(nq, 13), 256, 0, stream>>>(hB, Wp, bp, baseb32);
        for (int ch = 0; ch < 2; ch++) {
            int n0 = ch * NCH, n1 = n0 + NCH;
            k_msg<<<dim3(mq, 13), 256, 0, stream>>>(hB, csr, Wp, m32, offs, n0, n1);
            k_agg<<<2048, 192, 0, stream>>>(m32, offs, baseb32, agg32, n0, n1);
            k_post<<<dim3(5, cb), 256, 0, stream>>>(hN, offs, agg32, Wq, wqtl, bq, adl, tmp, n0, n1);
        }
        k_lin2<<<dim3(nb, 5), 256, 0, stream>>>(tmp, Wl, blp, zF, bnsum + l * 75, bnsq + l * 75);
        k_bn2<<<nb, 256, 0, stream>>>(zF, bnsum + l * 75, bnsq + l * 75,
                                      bn_g + l * 75, bn_b + l * 75, hN, hB);
    }

    float* t1 = tmp;
    k_mlp1<<<nb, 256, 0, stream>>>(hN, alpha, batch, mw1, mb1, t1);
    k_mlp2<<<nb, 256, 0, stream>>>(t1, mw2, mb2, mw3, mb3, noise, x, (float*)d_out);
}

// Round 11
// 2144.455 us; speedup vs baseline: 1.3476x; 1.1723x over previous
//
#include <hip/hip_runtime.h>
#include <hip/hip_bf16.h>
#include <cstdint>
#include <cstddef>

#define NN 30000
#define EE 150000
#define NCH 15000   // nodes per chunk (2 chunks)
#define ECH 80000   // m32 rows budget per chunk (~75000 expected)

using u16 = unsigned short;
using u32 = unsigned int;

__device__ __forceinline__ float bl2f(u16 u) { return __uint_as_float(((u32)u) << 16); }
__device__ __forceinline__ u16 f2bl(float f) {
    u32 x = __float_as_uint(f);
    return (u16)((x + 0x7fffu + ((x >> 16) & 1u)) >> 16);
}
__device__ __forceinline__ u32 pack2(float a, float b) {
    return (u32)f2bl(a) | ((u32)f2bl(b) << 16);
}

// ---------------- CSR build ----------------
__global__ void k_count(const int* __restrict__ dst, int* __restrict__ cnt) {
    int e = blockIdx.x * 256 + threadIdx.x;
    if (e < EE) atomicAdd(&cnt[dst[e]], 1);
}

__global__ void k_scan(const int* __restrict__ cnt, int* __restrict__ offs) {
    __shared__ int ss[1024];
    int t = threadIdx.x;
    int base = t * 30;
    int s = 0;
    for (int i = 0; i < 30; i++) { int idx = base + i; if (idx < NN) s += cnt[idx]; }
    ss[t] = s; __syncthreads();
    for (int off = 1; off < 1024; off <<= 1) {
        int v = (t >= off) ? ss[t - off] : 0;
        __syncthreads();
        ss[t] += v;
        __syncthreads();
    }
    int run = (t == 0) ? 0 : ss[t - 1];
    for (int i = 0; i < 30; i++) {
        int idx = base + i;
        if (idx < NN) { offs[idx] = run; run += cnt[idx]; }
    }
    if (t == 1023) offs[NN] = run;
}

__global__ void k_scatter(const int* __restrict__ src, const int* __restrict__ dst,
                          const int* __restrict__ offs, int* __restrict__ fill,
                          int* __restrict__ csr) {
    int e = blockIdx.x * 256 + threadIdx.x;
    if (e < EE) {
        int d = dst[e];
        int p = offs[d] + atomicAdd(&fill[d], 1);
        csr[p] = src[e];
    }
}

// ---------------- k_wqt: transpose agg-part of W_post into c-major layout --------
__global__ void k_wqt(const float* __restrict__ W_post, float* __restrict__ wqt) {
    int idx = blockIdx.x * 256 + threadIdx.x;
    if (idx >= 270000) return;
    int j = idx % 15;
    int grp = (idx / 15) % 3;
    int s4 = (idx / 45) % 4;
    int c = (idx / 180) % 75;
    int lt = idx / 13500;
    wqt[idx] = W_post[(size_t)lt * 975 * 15 + (size_t)(75 + grp * 300 + s4 * 75 + c) * 15 + j];
}

// ---------------- k_badj: bladj[l][c] = bl[c] + sum_k bq[k]*Wl[k][c]  (exact fold) ----
__global__ void k_badj(const float* __restrict__ b_lin, const float* __restrict__ b_post,
                       const float* __restrict__ W_lin, float* __restrict__ bladj) {
    int idx = blockIdx.x * 256 + threadIdx.x;
    if (idx >= 300) return;
    int l = idx / 75, c = idx % 75;
    float a = b_lin[l * 75 + c];
    const float* bq = b_post + l * 75;
    const float* Wl = W_lin + (size_t)l * 75 * 75;
    for (int k = 0; k < 75; k++) a = fmaf(bq[k], Wl[k * 75 + c], a);
    bladj[idx] = a;
}

// ---------------- pre linear: hN[n][80] f32 + hB[n][40] bf16 pairs ----------------
__global__ void k_pre(const float* __restrict__ x, const float* __restrict__ pw,
                      const float* __restrict__ pb, float* __restrict__ hN,
                      u32* __restrict__ hB) {
    int n = blockIdx.x * 256 + threadIdx.x;
    if (n >= NN) return;
    float x0 = x[2 * n], x1 = x[2 * n + 1];
    float buf[80];
#pragma unroll
    for (int c = 0; c < 80; c++)
        buf[c] = (c < 75) ? fmaf(x0, pw[c], fmaf(x1, pw[75 + c], pb[c])) : 0.f;
    float4* dstp = (float4*)(hN + (size_t)n * 80);
#pragma unroll
    for (int w = 0; w < 20; w++)
        dstp[w] = make_float4(buf[4 * w], buf[4 * w + 1], buf[4 * w + 2], buf[4 * w + 3]);
    uint4* bp4 = (uint4*)(hB + (size_t)n * 40);
#pragma unroll
    for (int w = 0; w < 10; w++)
        bp4[w] = make_uint4(pack2(buf[8 * w], buf[8 * w + 1]), pack2(buf[8 * w + 2], buf[8 * w + 3]),
                            pack2(buf[8 * w + 4], buf[8 * w + 5]), pack2(buf[8 * w + 6], buf[8 * w + 7]));
}

// ---- unpack helper: float k (0..7) from uint4 of bf16 pairs ----
__device__ __forceinline__ float upk(const uint4& a, int k) {
    u32 u = (k < 2) ? a.x : (k < 4) ? a.y : (k < 6) ? a.z : a.w;
    return __uint_as_float((k & 1) ? (u & 0xffff0000u) : (u << 16));
}

// ---- shared inner: 4 rows x 30 outputs, uniform weights (wA,wB 15-col slices) ----
__device__ __forceinline__ void gemm30q(const uint4* __restrict__ h0,
                                        const uint4* __restrict__ h1,
                                        const uint4* __restrict__ h2,
                                        const uint4* __restrict__ h3,
                                        const float* __restrict__ wA,
                                        const float* __restrict__ wB,
                                        float acc[4][30]) {
    for (int fq = 0; fq < 9; fq++) {
        uint4 a0 = h0[fq], a1 = h1[fq], a2 = h2[fq], a3 = h3[fq];
#pragma unroll
        for (int k = 0; k < 8; k++) {
            float i0 = upk(a0, k), i1 = upk(a1, k), i2 = upk(a2, k), i3 = upk(a3, k);
            const float* ra = wA + (fq * 8 + k) * 75;
            const float* rb = wB + (fq * 8 + k) * 75;
#pragma unroll
            for (int j = 0; j < 15; j++) {
                float w = ra[j];
                acc[0][j] = fmaf(i0, w, acc[0][j]); acc[1][j] = fmaf(i1, w, acc[1][j]);
                acc[2][j] = fmaf(i2, w, acc[2][j]); acc[3][j] = fmaf(i3, w, acc[3][j]);
            }
#pragma unroll
            for (int j = 0; j < 15; j++) {
                float w = rb[j];
                acc[0][15 + j] = fmaf(i0, w, acc[0][15 + j]); acc[1][15 + j] = fmaf(i1, w, acc[1][15 + j]);
                acc[2][15 + j] = fmaf(i2, w, acc[2][15 + j]); acc[3][15 + j] = fmaf(i3, w, acc[3][15 + j]);
            }
        }
    }
    uint4 a0 = h0[9], a1 = h1[9], a2 = h2[9], a3 = h3[9];
#pragma unroll
    for (int k = 0; k < 3; k++) {
        float i0 = upk(a0, k), i1 = upk(a1, k), i2 = upk(a2, k), i3 = upk(a3, k);
        const float* ra = wA + (72 + k) * 75;
        const float* rb = wB + (72 + k) * 75;
#pragma unroll
        for (int j = 0; j < 15; j++) {
            float w = ra[j];
            acc[0][j] = fmaf(i0, w, acc[0][j]); acc[1][j] = fmaf(i1, w, acc[1][j]);
            acc[2][j] = fmaf(i2, w, acc[2][j]); acc[3][j] = fmaf(i3, w, acc[3][j]);
        }
#pragma unroll
        for (int j = 0; j < 15; j++) {
            float w = rb[j];
            acc[0][15 + j] = fmaf(i0, w, acc[0][15 + j]); acc[1][15 + j] = fmaf(i1, w, acc[1][15 + j]);
            acc[2][15 + j] = fmaf(i2, w, acc[2][15 + j]); acc[3][15 + j] = fmaf(i3, w, acc[3][15 + j]);
        }
    }
}

// chunk p (0..12) -> weight slice pointers (15-col groups A and B)
__device__ __forceinline__ void chunk_w(int p, const float* Wp, int half_off,
                                        const float** wA, const float** wB, bool* full) {
    int cg = p * 2;
    int tA = cg / 5, cA = (cg % 5) * 15;
    *full = p < 12;
    int cg1 = *full ? cg + 1 : cg;
    int tB = cg1 / 5, cB = (cg1 % 5) * 15;
    *wA = Wp + ((size_t)tA * 150 + half_off) * 75 + cA;
    *wB = Wp + ((size_t)tB * 150 + half_off) * 75 + cB;
}

// ---------------- k_base: 4 nodes/thread x 13 chunks -> baseb32[n][188] --------
__global__ __launch_bounds__(256) void k_base(const u32* __restrict__ hB,
                                              const float* __restrict__ Wp,
                                              const float* __restrict__ bp,
                                              u32* __restrict__ baseb32) {
    int nq = blockIdx.x * 256 + threadIdx.x;
    if (nq >= 7500) return;
    int n = nq * 4;
    int p = blockIdx.y;
    const float *wA, *wB; bool full;
    chunk_w(p, Wp, 0, &wA, &wB, &full);
    int o0 = p * 30;
    float acc[4][30];
#pragma unroll
    for (int j = 0; j < 15; j++) {
        float b = bp[o0 + j];
        acc[0][j] = b; acc[1][j] = b; acc[2][j] = b; acc[3][j] = b;
    }
#pragma unroll
    for (int j = 0; j < 15; j++) {
        float b = full ? bp[o0 + 15 + j] : 0.f;
        acc[0][15 + j] = b; acc[1][15 + j] = b; acc[2][15 + j] = b; acc[3][15 + j] = b;
    }
    const uint4* h0 = (const uint4*)(hB + (size_t)(n + 0) * 40);
    const uint4* h1 = (const uint4*)(hB + (size_t)(n + 1) * 40);
    const uint4* h2 = (const uint4*)(hB + (size_t)(n + 2) * 40);
    const uint4* h3 = (const uint4*)(hB + (size_t)(n + 3) * 40);
    gemm30q(h0, h1, h2, h3, wA, wB, acc);
#pragma unroll
    for (int e = 0; e < 4; e++) {
        u32* row = baseb32 + (size_t)(n + e) * 188 + p * 15;
        if (full) {
#pragma unroll
            for (int w = 0; w < 15; w++) row[w] = pack2(acc[e][2 * w], acc[e][2 * w + 1]);
        } else {
#pragma unroll
            for (int w = 0; w < 7; w++) row[w] = pack2(acc[e][2 * w], acc[e][2 * w + 1]);
            row[7] = pack2(acc[e][14], 0.f);
        }
    }
}

// ---------------- k_msg: 4 edges/thread x 13 chunks -> m32[row][188] ----------
__global__ __launch_bounds__(256) void k_msg(const u32* __restrict__ hB,
                                             const int* __restrict__ csr,
                                             const float* __restrict__ Wp,
                                             u32* __restrict__ m32,
                                             const int* __restrict__ offs,
                                             int n0, int n1) {
    int e_begin = offs[n0], e_end = offs[n1];
    int e = e_begin + (blockIdx.x * 256 + threadIdx.x) * 4;
    if (e >= e_end) return;
    int p = blockIdx.y;
    const float *wA, *wB; bool full;
    chunk_w(p, Wp, 75, &wA, &wB, &full);
    int e1c = e + 1 < e_end ? e + 1 : e_end - 1;
    int e2c = e + 2 < e_end ? e + 2 : e_end - 1;
    int e3c = e + 3 < e_end ? e + 3 : e_end - 1;
    int s0 = csr[e], s1 = csr[e1c], s2 = csr[e2c], s3 = csr[e3c];
    float acc[4][30];
#pragma unroll
    for (int e4 = 0; e4 < 4; e4++)
#pragma unroll
        for (int j = 0; j < 30; j++) acc[e4][j] = 0.f;
    const uint4* h0 = (const uint4*)(hB + (size_t)s0 * 40);
    const uint4* h1 = (const uint4*)(hB + (size_t)s1 * 40);
    const uint4* h2 = (const uint4*)(hB + (size_t)s2 * 40);
    const uint4* h3 = (const uint4*)(hB + (size_t)s3 * 40);
    gemm30q(h0, h1, h2, h3, wA, wB, acc);
#pragma unroll
    for (int e4 = 0; e4 < 4; e4++) {
        if (e + e4 >= e_end) break;
        u32* row = m32 + (size_t)(e + e4 - e_begin) * 188 + p * 15;
        if (full) {
#pragma unroll
            for (int w = 0; w < 15; w++) row[w] = pack2(acc[e4][2 * w], acc[e4][2 * w + 1]);
        } else {
#pragma unroll
            for (int w = 0; w < 7; w++) row[w] = pack2(acc[e4][2 * w], acc[e4][2 * w + 1]);
            row[7] = pack2(acc[e4][14], 0.f);
        }
    }
}

// ---------------- k_agg: per-node stats over chunk-relative m32 rows (188 layout) ----
__global__ __launch_bounds__(192) void k_agg(const u32* __restrict__ m32,
                                             const int* __restrict__ offs,
                                             const u32* __restrict__ baseb32,
                                             u32* __restrict__ agg32,
                                             int n0, int n1) {
    int q = threadIdx.x;
    if (q >= 188) return;
    int e_base = offs[n0];
    int o0 = 2 * q, o1 = 2 * q + 1;
    bool has1 = o1 < 375;
    int t0 = o0 / 75, c0 = o0 % 75;
    int t1 = has1 ? (o1 / 75) : 0, c1 = has1 ? (o1 % 75) : 0;
    for (int v = n0 + blockIdx.x; v < n1; v += gridDim.x) {
        int e0 = offs[v], e1 = offs[v + 1];
        float s0 = 0.f, s1 = 0.f, sq0 = 0.f, sq1 = 0.f;
        float mn0 = 3.4e38f, mn1 = 3.4e38f, mx0 = -3.4e38f, mx1 = -3.4e38f;
        for (int e = e0; e < e1; e++) {
            u32 w = m32[(size_t)(e - e_base) * 188 + q];
            float x0 = bl2f((u16)(w & 0xffffu)), x1 = bl2f((u16)(w >> 16));
            s0 += x0; sq0 = fmaf(x0, x0, sq0); mn0 = fminf(mn0, x0); mx0 = fmaxf(mx0, x0);
            s1 += x1; sq1 = fmaf(x1, x1, sq1); mn1 = fminf(mn1, x1); mx1 = fmaxf(mx1, x1);
        }
        int deg = e1 - e0;
        u32 bw = baseb32[(size_t)v * 188 + q];
        float b0 = bl2f((u16)(bw & 0xffffu)), b1 = bl2f((u16)(bw >> 16));
        float mean0, mean1, mnf0, mnf1, mxf0, mxf1, sd0, sd1;
        if (deg > 0) {
            float im = 1.f / (float)deg;
            float mm0 = s0 * im, mm1 = s1 * im;
            float v0 = fmaxf(fmaf(-mm0, mm0, sq0 * im), 0.f);
            float v1 = fmaxf(fmaf(-mm1, mm1, sq1 * im), 0.f);
            sd0 = sqrtf(v0 + 1e-5f); sd1 = sqrtf(v1 + 1e-5f);
            mean0 = b0 + mm0; mean1 = b1 + mm1;
            mnf0 = b0 + mn0;  mnf1 = b1 + mn1;
            mxf0 = b0 + mx0;  mxf1 = b1 + mx1;
        } else {
            float sde = sqrtf(1e-5f);
            mean0 = mean1 = mnf0 = mnf1 = mxf0 = mxf1 = 0.f;
            sd0 = sd1 = sde;
        }
        u32* ap = agg32 + (size_t)(v - n0) * 768;
        ap[t0 * 152 + c0] = pack2(mean0, mnf0);
        ap[t0 * 152 + 76 + c0] = pack2(mxf0, sd0);
        if (has1) {
            ap[t1 * 152 + c1] = pack2(mean1, mnf1);
            ap[t1 * 152 + 76 + c1] = pack2(mxf1, sd1);
        }
    }
}

// ---------------- k_post: (tower, node-block, c-slice) partials via atomicAdd ----
__global__ __launch_bounds__(256) void k_post(const float* __restrict__ hN,
                                              const int* __restrict__ offs,
                                              const u32* __restrict__ agg32,
                                              const float* __restrict__ Wq,
                                              const float* __restrict__ wqt_l,
                                              const float* __restrict__ adl_p,
                                              float* __restrict__ tmp,
                                              int n0, int n1) {
    int t = blockIdx.x;
    int zz = blockIdx.z;               // 0..2 c-slice
    int n = n0 + blockIdx.y * 256 + threadIdx.x;
    if (n >= n1) return;
    float adl = adl_p[0];
    int deg = offs[n + 1] - offs[n];
    float dc = (float)(deg > 0 ? deg : 1);
    float amp = log1pf(dc) / adl;
    float inv = 1.f / amp;
    const float* wq = wqt_l + (size_t)t * 13500;
    float acc[15];
#pragma unroll
    for (int j = 0; j < 15; j++) acc[j] = 0.f;
    if (zz == 0) {
        const float* wt = Wq + (size_t)t * 975 * 15;
        const float4* hp4 = (const float4*)(hN + (size_t)n * 80);
#pragma unroll
        for (int fq = 0; fq < 19; fq++) {
            float4 h4 = hp4[fq];
#pragma unroll
            for (int k2 = 0; k2 < 4; k2++) {
                int kk = fq * 4 + k2;
                if (kk < 75) {
                    float in = (k2 == 0) ? h4.x : (k2 == 1) ? h4.y : (k2 == 2) ? h4.z : h4.w;
                    const float* wr = wt + kk * 15;
#pragma unroll
                    for (int j = 0; j < 15; j++) acc[j] = fmaf(in, wr[j], acc[j]);
                }
            }
        }
    }
    int cq_lo = (zz == 0) ? 0 : (zz == 1) ? 6 : 13;
    int cq_hi = (zz == 0) ? 6 : (zz == 1) ? 13 : 19;
    const uint4* apA = (const uint4*)(agg32 + (size_t)(n - n0) * 768 + t * 152);
    const uint4* apB = (const uint4*)(agg32 + (size_t)(n - n0) * 768 + t * 152 + 76);
    for (int cq = cq_lo; cq < cq_hi; cq++) {
        uint4 A = apA[cq];
        uint4 B = apB[cq];
#pragma unroll
        for (int i = 0; i < 4; i++) {
            int c = cq * 4 + i;
            if (c < 75) {
                u32 wA = (i == 0) ? A.x : (i == 1) ? A.y : (i == 2) ? A.z : A.w;
                u32 wB = (i == 0) ? B.x : (i == 1) ? B.y : (i == 2) ? B.z : B.w;
                float vs[4];
                vs[0] = bl2f((u16)(wA & 0xffffu)); vs[1] = bl2f((u16)(wA >> 16));
                vs[2] = bl2f((u16)(wB & 0xffffu)); vs[3] = bl2f((u16)(wB >> 16));
                const float* wc = wq + c * 180;
#pragma unroll
                for (int s4 = 0; s4 < 4; s4++) {
                    float a = vs[s4], aa = a * amp, ai = a * inv;
                    const float* wb = wc + s4 * 45;
#pragma unroll
                    for (int j = 0; j < 15; j++)
                        acc[j] = fmaf(a, wb[j], fmaf(aa, wb[15 + j], fmaf(ai, wb[30 + j], acc[j])));
                }
            }
        }
    }
#pragma unroll
    for (int j = 0; j < 15; j++)
        atomicAdd(&tmp[(size_t)(t * 15 + j) * NN + n], acc[j]);
}

// ---------------- k_lin2: (nodes x 5 chunks), LDS-staged Wl slice, zF out ----------
__global__ __launch_bounds__(256) void k_lin2(const float* __restrict__ tmp,
                                              const float* __restrict__ Wl,
                                              const float* __restrict__ bladj,
                                              float* __restrict__ zF,
                                              float* __restrict__ bsum,
                                              float* __restrict__ bsq) {
    __shared__ __align__(16) float wl[75][16];
    __shared__ float red1[4][15], red2[4][15];
    int p = blockIdx.y;
    for (int idx = threadIdx.x; idx < 75 * 15; idx += 256) {
        int k = idx / 15, j = idx % 15;
        wl[k][j] = Wl[k * 75 + p * 15 + j];
    }
    __syncthreads();
    int n = blockIdx.x * 256 + threadIdx.x;
    bool valid = n < NN;
    int nc = valid ? n : NN - 1;
    float acc[15];
#pragma unroll
    for (int j = 0; j < 15; j++) acc[j] = bladj[p * 15 + j];
    for (int k = 0; k < 75; k++) {
        float in = tmp[(size_t)k * NN + nc];
        float4 w0 = *(const float4*)&wl[k][0];
        float4 w1 = *(const float4*)&wl[k][4];
        float4 w2 = *(const float4*)&wl[k][8];
        float4 w3 = *(const float4*)&wl[k][12];
        acc[0] = fmaf(in, w0.x, acc[0]);  acc[1] = fmaf(in, w0.y, acc[1]);
        acc[2] = fmaf(in, w0.z, acc[2]);  acc[3] = fmaf(in, w0.w, acc[3]);
        acc[4] = fmaf(in, w1.x, acc[4]);  acc[5] = fmaf(in, w1.y, acc[5]);
        acc[6] = fmaf(in, w1.z, acc[6]);  acc[7] = fmaf(in, w1.w, acc[7]);
        acc[8] = fmaf(in, w2.x, acc[8]);  acc[9] = fmaf(in, w2.y, acc[9]);
        acc[10] = fmaf(in, w2.z, acc[10]); acc[11] = fmaf(in, w2.w, acc[11]);
        acc[12] = fmaf(in, w3.x, acc[12]); acc[13] = fmaf(in, w3.y, acc[13]);
        acc[14] = fmaf(in, w3.z, acc[14]);
    }
    if (valid) {
#pragma unroll
        for (int j = 0; j < 15; j++)
            zF[(size_t)(p * 15 + j) * NN + n] = acc[j];
    }
    float s[15], ss[15];
#pragma unroll
    for (int i = 0; i < 15; i++) {
        float a = valid ? acc[i] : 0.f;
        s[i] = a; ss[i] = a * a;
    }
    for (int d = 32; d > 0; d >>= 1) {
#pragma unroll
        for (int i = 0; i < 15; i++) {
            s[i] += __shfl_down(s[i], d);
            ss[i] += __shfl_down(ss[i], d);
        }
    }
    int wave = threadIdx.x >> 6, lane = threadIdx.x & 63;
    if (lane == 0) {
#pragma unroll
        for (int i = 0; i < 15; i++) { red1[wave][i] = s[i]; red2[wave][i] = ss[i]; }
    }
    __syncthreads();
    if (threadIdx.x < 15) {
        int i = threadIdx.x;
        float a = red1[0][i] + red1[1][i] + red1[2][i] + red1[3][i];
        float b = red2[0][i] + red2[1][i] + red2[2][i] + red2[3][i];
        atomicAdd(&bsum[p * 15 + i], a);
        atomicAdd(&bsq[p * 15 + i], b);
    }
}

// ---------------- k_bn2: BN + ReLU, zF -> hN f32 + hB bf16 ----------
__global__ __launch_bounds__(256) void k_bn2(const float* __restrict__ zF,
                                             const float* __restrict__ bsum,
                                             const float* __restrict__ bsq,
                                             const float* __restrict__ g,
                                             const float* __restrict__ b,
                                             float* __restrict__ hN,
                                             u32* __restrict__ hB) {
    int n = blockIdx.x * 256 + threadIdx.x;
    if (n >= NN) return;
    float buf[80];
    for (int c = 0; c < 75; c++) {
        float mu = bsum[c] * (1.f / NN);
        float var = bsq[c] * (1.f / NN) - mu * mu;
        float sc = g[c] * rsqrtf(var + 1e-5f);
        float v = (zF[(size_t)c * NN + n] - mu) * sc + b[c];
        buf[c] = v > 0.f ? v : 0.f;
    }
#pragma unroll
    for (int c = 75; c < 80; c++) buf[c] = 0.f;
    float4* dstp = (float4*)(hN + (size_t)n * 80);
#pragma unroll
    for (int w = 0; w < 20; w++)
        dstp[w] = make_float4(buf[4 * w], buf[4 * w + 1], buf[4 * w + 2], buf[4 * w + 3]);
    uint4* bp4 = (uint4*)(hB + (size_t)n * 40);
#pragma unroll
    for (int w = 0; w < 10; w++)
        bp4[w] = make_uint4(pack2(buf[8 * w], buf[8 * w + 1]), pack2(buf[8 * w + 2], buf[8 * w + 3]),
                            pack2(buf[8 * w + 4], buf[8 * w + 5]), pack2(buf[8 * w + 6], buf[8 * w + 7]));
}

// ---------------- MLP head ----------------
__global__ __launch_bounds__(256) void k_mlp1(const float* __restrict__ hN,
                                              const float* __restrict__ alpha,
                                              const int* __restrict__ batch,
                                              const float* __restrict__ w1,
                                              const float* __restrict__ b1,
                                              float* __restrict__ t1) {
    int n = blockIdx.x * 256 + threadIdx.x;
    if (n >= NN) return;
    float acc[50];
#pragma unroll
    for (int j = 0; j < 50; j++) acc[j] = b1[j];
    const float4* hp4 = (const float4*)(hN + (size_t)n * 80);
#pragma unroll
    for (int fq = 0; fq < 19; fq++) {
        float4 h4 = hp4[fq];
#pragma unroll
        for (int k2 = 0; k2 < 4; k2++) {
            int kk = fq * 4 + k2;
            if (kk < 75) {
                float in = (k2 == 0) ? h4.x : (k2 == 1) ? h4.y : (k2 == 2) ? h4.z : h4.w;
                const float* wr = w1 + kk * 50;
#pragma unroll
                for (int j = 0; j < 50; j++) acc[j] = fmaf(in, wr[j], acc[j]);
            }
        }
    }
    float a = alpha[batch[n]];
    const float* wr = w1 + 75 * 50;
#pragma unroll
    for (int j = 0; j < 50; j++) {
        float v = fmaf(a, wr[j], acc[j]);
        t1[(size_t)j * NN + n] = v > 0.f ? v : 0.f;
    }
}

__global__ void k_mlp2(const float* __restrict__ t1, const float* __restrict__ w2,
                       const float* __restrict__ b2, const float* __restrict__ w3,
                       const float* __restrict__ b3, const float* __restrict__ noise,
                       const float* __restrict__ x, float* __restrict__ out) {
    int n = blockIdx.x * 256 + threadIdx.x;
    if (n >= NN) return;
    float tr[50];
#pragma unroll
    for (int k = 0; k < 50; k++) tr[k] = t1[(size_t)k * NN + n];
    float y = b3[0];
#pragma unroll
    for (int k2 = 0; k2 < 25; k2++) {
        float acc = b2[k2];
#pragma unroll
        for (int k = 0; k < 50; k++) acc = fmaf(tr[k], w2[k * 25 + k2], acc);
        acc = acc > 0.f ? acc : 0.f;
        y = fmaf(acc, w3[k2], y);
    }
    float z = y + noise[n];
    float s = 1.f / (1.f + expf(-z));
    out[n] = s;
    out[NN + n] = x[2 * n];
}

extern "C" void kernel_launch(void* const* d_in, const int* in_sizes, int n_in,
                              void* d_out, int out_size, void* d_ws, size_t ws_size,
                              hipStream_t stream) {
    const float* x      = (const float*)d_in[0];
    const float* alpha  = (const float*)d_in[1];
    const int*   ei     = (const int*)d_in[2];
    const int*   batch  = (const int*)d_in[3];
    const float* noise  = (const float*)d_in[4];
    const float* adl    = (const float*)d_in[5];
    const float* pre_w  = (const float*)d_in[6];
    const float* pre_b  = (const float*)d_in[7];
    const float* W_pre  = (const float*)d_in[8];
    const float* b_pre  = (const float*)d_in[9];
    const float* W_post = (const float*)d_in[10];
    const float* b_post = (const float*)d_in[11];
    const float* W_lin  = (const float*)d_in[12];
    const float* b_lin  = (const float*)d_in[13];
    const float* bn_g   = (const float*)d_in[14];
    const float* bn_b   = (const float*)d_in[15];
    const float* mw1    = (const float*)d_in[16];
    const float* mb1    = (const float*)d_in[17];
    const float* mw2    = (const float*)d_in[18];
    const float* mb2    = (const float*)d_in[19];
    const float* mw3    = (const float*)d_in[20];
    const float* mb3    = (const float*)d_in[21];
    (void)in_sizes; (void)n_in; (void)out_size; (void)ws_size;

    char* ws = (char*)d_ws;
    size_t off = 0;
    auto alloc = [&](size_t bytes) -> char* {
        char* p = ws + off;
        off += (bytes + 255) & ~((size_t)255);
        return p;
    };
    float* hN     = (float*)alloc((size_t)NN * 80 * 4);        //  9.6 MB
    u32*   hB     = (u32*)alloc((size_t)NN * 40 * 4);          //  4.8 MB
    float* zF     = (float*)alloc((size_t)75 * NN * 4);        //  9.0 MB
    float* tmp    = (float*)alloc((size_t)75 * NN * 4);        //  9.0 MB
    u32*   agg32  = (u32*)alloc((size_t)NCH * 768 * 4);        // 46.1 MB
    u32*   baseb32= (u32*)alloc((size_t)NN * 188 * 4);         // 22.6 MB
    u32*   m32    = (u32*)alloc((size_t)ECH * 188 * 4);        // 60.2 MB
    float* wqt    = (float*)alloc((size_t)270000 * 4);         //  1.1 MB
    float* bladj  = (float*)alloc(300 * 4);
    int*   cnt    = (int*)alloc((size_t)NN * 4);
    int*   offs   = (int*)alloc((size_t)(NN + 1) * 4);
    int*   fill   = (int*)alloc((size_t)NN * 4);
    int*   csr    = (int*)alloc((size_t)EE * 4);
    float* bnsum  = (float*)alloc(4 * 75 * 4);
    float* bnsq   = (float*)alloc(4 * 75 * 4);

    hipMemsetAsync(cnt, 0, (size_t)NN * 4, stream);
    hipMemsetAsync(fill, 0, (size_t)NN * 4, stream);
    hipMemsetAsync(bnsum, 0, 4 * 75 * 4, stream);
    hipMemsetAsync(bnsq, 0, 4 * 75 * 4, stream);

    const int* src = ei;
    const int* dst = ei + EE;
    int eb = (EE + 255) / 256;
    int nb = (NN + 255) / 256;
    int cb = (NCH + 255) / 256;
    int nq = (7500 + 255) / 256;             // node quads
    int mq = (ECH / 4 + 255) / 256;          // edge quads (worst case)

    k_count<<<eb, 256, 0, stream>>>(dst, cnt);
    k_scan<<<1, 1024, 0, stream>>>(cnt, offs);
    k_scatter<<<eb, 256, 0, stream>>>(src, dst, offs, fill, csr);
    k_pre<<<nb, 256, 0, stream>>>(x, pre_w, pre_b, hN, hB);
    k_wqt<<<(270000 + 255) / 256, 256, 0, stream>>>(W_post, wqt);
    k_badj<<<2, 256, 0, stream>>>(b_lin, b_post, W_lin, bladj);

    for (int l = 0; l < 4; l++) {
        const float* Wp  = W_pre + (size_t)l * 5 * 150 * 75;
        const float* bp  = b_pre + l * 375;
        const float* Wq  = W_post + (size_t)l * 5 * 975 * 15;
        const float* wqtl= wqt + (size_t)l * 67500;
        const float* Wl  = W_lin + l * 75 * 75;
        k_base<<<dim3(nq, 13), 256, 0, stream>>>(hB, Wp, bp, baseb32);
        hipMemsetAsync(tmp, 0, (size_t)75 * NN * 4, stream);
        for (int ch = 0; ch < 2; ch++) {
            int n0 = ch * NCH, n1 = n0 + NCH;
            k_msg<<<dim3(mq, 13), 256, 0, stream>>>(hB, csr, Wp, m32, offs, n0, n1);
            k_agg<<<2048, 192, 0, stream>>>(m32, offs, baseb32, agg32, n0, n1);
            k_post<<<dim3(5, cb, 3), 256, 0, stream>>>(hN, offs, agg32, Wq, wqtl, adl, tmp, n0, n1);
        }
        k_lin2<<<dim3(nb, 5), 256, 0, stream>>>(tmp, Wl, bladj + l * 75, zF,
                                                bnsum + l * 75, bnsq + l * 75);
        k_bn2<<<nb, 256, 0, stream>>>(zF, bnsum + l * 75, bnsq + l * 75,
                                      bn_g + l * 75, bn_b + l * 75, hN, hB);
    }

    float* t1 = tmp;
    k_mlp1<<<nb, 256, 0, stream>>>(hN, alpha, batch, mw1, mb1, t1);
    k_mlp2<<<nb, 256, 0, stream>>>(t1, mw2, mb2, mw3, mb3, noise, x, (float*)d_out);
}